// Round 4
// baseline (351.984 us; speedup 1.0000x reference)
//
#include <hip/hip_runtime.h>
#include <hip/hip_bf16.h>

typedef unsigned short u16;
typedef __attribute__((ext_vector_type(8))) short bf16x8;  // 8 bf16 = 4 VGPRs
typedef __attribute__((ext_vector_type(4))) float f32x4;

// ---------------- helpers ----------------

__device__ __forceinline__ u16 f2bf(float f) {
  union { float f; unsigned u; } v; v.f = f;
  unsigned r = v.u + 0x7fffu + ((v.u >> 16) & 1u);  // RNE
  return (u16)(r >> 16);
}

// pack two fp32 -> two bf16 in one dword (HW packed cvt when available)
#if defined(__has_builtin)
#if __has_builtin(__builtin_amdgcn_cvt_pk_bf16_f32)
#define HAS_PK_BF16 1
#endif
#endif
__device__ __forceinline__ unsigned pk2bf(float a, float b) {
#ifdef HAS_PK_BF16
  typedef __attribute__((ext_vector_type(2))) __bf16 vbf2;
  union { vbf2 v; unsigned u; } u;
  u.v = __builtin_amdgcn_cvt_pk_bf16_f32(a, b);
  return u.u;
#else
  return (unsigned)f2bf(a) | ((unsigned)f2bf(b) << 16);
#endif
}

__device__ __forceinline__ f32x4 mfma16(bf16x8 a, bf16x8 b, f32x4 c) {
  return __builtin_amdgcn_mfma_f32_16x16x32_bf16(a, b, c, 0, 0, 0);
}

// async global->LDS, 16B per lane. LDS dest = wave-uniform base + lane*16.
__device__ __forceinline__ void gl_lds16(const void* g, void* l) {
  __builtin_amdgcn_global_load_lds((__attribute__((address_space(1))) void*)g,
                                   (__attribute__((address_space(3))) void*)l,
                                   16, 0, 0);
}

// stage a 128-row x 32-col bf16 tile (8 KB) from row-major global (row len ld)
__device__ __forceinline__ void stage128x32(const u16* g0, int ld, u16* lds) {
  const int t = threadIdx.x;
  const int wave = t >> 6;
#pragma unroll
  for (int j = 0; j < 2; ++j) {
    int c = j * 256 + t;                       // chunk 0..511
    const u16* gp = g0 + (size_t)(c >> 2) * ld + (c & 3) * 8;
    gl_lds16(gp, lds + (size_t)(j * 256 + wave * 64) * 8);
  }
}

// ---------------- conversion kernels ----------------

__global__ void cvt_f32_bf16(const float* __restrict__ in, u16* __restrict__ out, int n) {
  int i = (blockIdx.x * blockDim.x + threadIdx.x) * 4;
  if (i >= n) return;
  float4 v = *(const float4*)(in + i);
  u16 o0 = f2bf(v.x), o1 = f2bf(v.y), o2 = f2bf(v.z), o3 = f2bf(v.w);
  ushort4 o; o.x = o0; o.y = o1; o.z = o2; o.w = o3;
  *(ushort4*)(out + i) = o;
}

// out[c][r] = bf16(in[r][c]); in is [R][C] fp32, out is [C][R] bf16
__global__ void transpose_cvt(const float* __restrict__ in, u16* __restrict__ out,
                              int R, int C) {
  __shared__ u16 tile[64][65];
  int c0 = blockIdx.x * 64, r0 = blockIdx.y * 64;
  int lc = threadIdx.x & 63, lr = threadIdx.x >> 6;
#pragma unroll
  for (int i = 0; i < 16; ++i) {
    int r = lr + i * 4;
    tile[r][lc] = f2bf(in[(size_t)(r0 + r) * C + c0 + lc]);
  }
  __syncthreads();
#pragma unroll
  for (int i = 0; i < 16; ++i) {
    int c = lr + i * 4;
    out[(size_t)(c0 + c) * R + r0 + lc] = tile[lc][c];
  }
}

// V [bh][2048][64] -> Vt [bh][64][2048]  (bf16)
__global__ void transpose_v(const u16* __restrict__ Vb, u16* __restrict__ Vt) {
  __shared__ u16 tile[64][65];
  int bh = blockIdx.y;
  int s0 = blockIdx.x * 64;
  const u16* in = Vb + (size_t)bh * 2048 * 64;
  u16* out = Vt + (size_t)bh * 64 * 2048;
  int lc = threadIdx.x & 63, lr = threadIdx.x >> 6;
#pragma unroll
  for (int i = 0; i < 16; ++i) {
    int r = lr + i * 4;
    tile[r][lc] = in[(size_t)(s0 + r) * 64 + lc];
  }
  __syncthreads();
#pragma unroll
  for (int i = 0; i < 16; ++i) {
    int d = lr + i * 4;
    out[(size_t)d * 2048 + s0 + lc] = tile[lc][d];
  }
}

// ---------------- GEMM 1: qkv = x @ w_qkv + b_qkv ----------------
// Q pre-scaled by SCALE*log2(e) so QK^T MFMA emits exp2 arguments directly.

__global__ __launch_bounds__(256, 2) void gemm_qkv(
    const u16* __restrict__ A, const u16* __restrict__ Bt,
    const float* __restrict__ bias,
    u16* __restrict__ Qb, u16* __restrict__ Kb, u16* __restrict__ Vb) {
  __shared__ u16 As[128 * 32], Bs[128 * 32];
  const int row0 = blockIdx.x * 128, col0 = blockIdx.y * 128;
  const int t = threadIdx.x, lane = t & 63, wave = t >> 6;
  const int quad = lane >> 4, l15 = lane & 15;
  const int m_off = (wave & 1) * 64, n_off = (wave >> 1) * 64;
  f32x4 acc[4][4] = {};
  for (int k0 = 0; k0 < 1024; k0 += 32) {
    __syncthreads();
    stage128x32(A + (size_t)row0 * 1024 + k0, 1024, As);
    stage128x32(Bt + (size_t)col0 * 1024 + k0, 1024, Bs);
    __syncthreads();
    bf16x8 a[4], b[4];
#pragma unroll
    for (int mi = 0; mi < 4; ++mi)
      a[mi] = *(const bf16x8*)(As + (m_off + mi * 16 + l15) * 32 + quad * 8);
#pragma unroll
    for (int ni = 0; ni < 4; ++ni)
      b[ni] = *(const bf16x8*)(Bs + (n_off + ni * 16 + l15) * 32 + quad * 8);
#pragma unroll
    for (int mi = 0; mi < 4; ++mi)
#pragma unroll
      for (int ni = 0; ni < 4; ++ni)
        acc[mi][ni] = mfma16(a[mi], b[ni], acc[mi][ni]);
  }
  const int which = col0 >> 10;  // block-uniform: 0=Q 1=K 2=V
  u16* dst = which == 0 ? Qb : (which == 1 ? Kb : Vb);
  const float qscale = which == 0 ? 0.1803368801111137f : 1.0f;  // 0.125*log2(e)
#pragma unroll
  for (int ni = 0; ni < 4; ++ni) {
    int col = col0 + n_off + ni * 16 + l15;
    float bv = bias[col];
    int h = (col >> 6) & 15, d = col & 63;
#pragma unroll
    for (int mi = 0; mi < 4; ++mi) {
#pragma unroll
      for (int r = 0; r < 4; ++r) {
        int row = row0 + m_off + mi * 16 + quad * 4 + r;  // b*2048 + s
        int bb = row >> 11, s = row & 2047;
        float v = (acc[mi][ni][r] + bv) * qscale;
        dst[(((size_t)bb * 16 + h) * 2048 + s) * 64 + d] = f2bf(v);
      }
    }
  }
}

// ---------------- GEMM 2: out = attn_out @ w_proj + b_proj (fp32 out) ----------------

__global__ __launch_bounds__(256, 2) void gemm_proj(
    const u16* __restrict__ A, const u16* __restrict__ Bt,
    const float* __restrict__ bias, float* __restrict__ C) {
  __shared__ u16 As[128 * 32], Bs[128 * 32];
  const int row0 = blockIdx.x * 128, col0 = blockIdx.y * 128;
  const int t = threadIdx.x, lane = t & 63, wave = t >> 6;
  const int quad = lane >> 4, l15 = lane & 15;
  const int m_off = (wave & 1) * 64, n_off = (wave >> 1) * 64;
  f32x4 acc[4][4] = {};
  for (int k0 = 0; k0 < 1024; k0 += 32) {
    __syncthreads();
    stage128x32(A + (size_t)row0 * 1024 + k0, 1024, As);
    stage128x32(Bt + (size_t)col0 * 1024 + k0, 1024, Bs);
    __syncthreads();
    bf16x8 a[4], b[4];
#pragma unroll
    for (int mi = 0; mi < 4; ++mi)
      a[mi] = *(const bf16x8*)(As + (m_off + mi * 16 + l15) * 32 + quad * 8);
#pragma unroll
    for (int ni = 0; ni < 4; ++ni)
      b[ni] = *(const bf16x8*)(Bs + (n_off + ni * 16 + l15) * 32 + quad * 8);
#pragma unroll
    for (int mi = 0; mi < 4; ++mi)
#pragma unroll
      for (int ni = 0; ni < 4; ++ni)
        acc[mi][ni] = mfma16(a[mi], b[ni], acc[mi][ni]);
  }
#pragma unroll
  for (int ni = 0; ni < 4; ++ni) {
    int col = col0 + n_off + ni * 16 + l15;
    float bv = bias[col];
#pragma unroll
    for (int mi = 0; mi < 4; ++mi) {
#pragma unroll
      for (int r = 0; r < 4; ++r) {
        int row = row0 + m_off + mi * 16 + quad * 4 + r;
        C[(size_t)row * 1024 + col] = acc[mi][ni][r] + bv;
      }
    }
  }
}

// ---------------- Flash attention v3: key-split waves, global->VGPR, LDS-free loop --------
// Q,K: [bh][2048][64] bf16 (Q pre-scaled by 0.125*log2e); Vt: [bh][64][2048] bf16.
// p = exp2(s) with NO shift: |s|max ~ 9 << 127 (fp32 exp range); l-normalization cancels
// all scaling exactly (softmax shift-invariance). Order-free sum -> waves split KEYS:
// block = 64 q, 4 waves; wave w handles keys {it*128 + w*32 + 0..31}, 16 iterations.
// All operands (K, V, Q) load global->VGPR b128 (L2-resident; K+V reread = 32x = 1 GB).
// P round-trips a per-wave-private 5 KB LDS scratch (b64 write / b128 read, no barrier).
// Cross-wave O/l merge once at the end through LDS.

__global__ __launch_bounds__(256, 3) void attn_kernel(
    const u16* __restrict__ Qb, const u16* __restrict__ Kb,
    const u16* __restrict__ Vt, u16* __restrict__ Ob) {
  __shared__ u16 Pbuf[4][64 * 40];   // per-wave P [64 q][32 key], row pad 40 (2-way banks)
  __shared__ float l_buf[4][64];
  float* Obuf = (float*)&Pbuf[0][0]; // reused as [64 d][68 q] f32 after final barrier

  const int q0 = blockIdx.x * 64, bh = blockIdx.y;
  const u16* Qp = Qb + (size_t)bh * 2048 * 64;
  const u16* Kp = Kb + (size_t)bh * 2048 * 64;
  const u16* Vp = Vt + (size_t)bh * 64 * 2048;
  const int t = threadIdx.x, lane = t & 63, wave = t >> 6;
  const int quad = lane >> 4, l15 = lane & 15;
  u16* Pw = &Pbuf[wave][0];

  // Q fragments in registers for the whole kernel: B[k=d][n=q]
  bf16x8 qf[2][4];
#pragma unroll
  for (int ks = 0; ks < 2; ++ks)
#pragma unroll
    for (int nq = 0; nq < 4; ++nq)
      qf[ks][nq] = *(const bf16x8*)(Qp + (size_t)(q0 + nq * 16 + l15) * 64 + ks * 32 + quad * 8);

  float l_part[4] = {0.f, 0.f, 0.f, 0.f};
  f32x4 acc[4][4] = {};  // [mq][nd]: O rows q=mq*16+quad*4+r, cols d=nd*16+l15

  for (int it = 0; it < 16; ++it) {
    const int key0 = it * 128 + wave * 32;
    // K fragments: A[m=key][k=d]
    bf16x8 kf[2][2];
#pragma unroll
    for (int mk = 0; mk < 2; ++mk)
#pragma unroll
      for (int ks = 0; ks < 2; ++ks)
        kf[mk][ks] = *(const bf16x8*)(Kp + (size_t)(key0 + mk * 16 + l15) * 64 + ks * 32 + quad * 8);
    // V fragments: B[k=key][n=d] from Vt[d][key]
    bf16x8 vb[4];
#pragma unroll
    for (int nd = 0; nd < 4; ++nd)
      vb[nd] = *(const bf16x8*)(Vp + (size_t)(nd * 16 + l15) * 2048 + key0 + quad * 8);

    // S^T = K.Q^T : C[row=key=mk*16+quad*4+r][col=q=nq*16+l15]
    f32x4 s[2][4] = {};
#pragma unroll
    for (int ks = 0; ks < 2; ++ks)
#pragma unroll
      for (int mk = 0; mk < 2; ++mk)
#pragma unroll
        for (int nq = 0; nq < 4; ++nq)
          s[mk][nq] = mfma16(kf[mk][ks], qf[ks][nq], s[mk][nq]);

    // p = exp2(s); accumulate l; write P to private LDS in PV A-layout
#pragma unroll
    for (int mk = 0; mk < 2; ++mk)
#pragma unroll
      for (int nq = 0; nq < 4; ++nq) {
        float p0 = __builtin_amdgcn_exp2f(s[mk][nq][0]);
        float p1 = __builtin_amdgcn_exp2f(s[mk][nq][1]);
        float p2 = __builtin_amdgcn_exp2f(s[mk][nq][2]);
        float p3 = __builtin_amdgcn_exp2f(s[mk][nq][3]);
        l_part[nq] += (p0 + p1) + (p2 + p3);
        uint2 pk; pk.x = pk2bf(p0, p1); pk.y = pk2bf(p2, p3);
        // row q = nq*16+l15 (40 u16 pitch), cols key mk*16+quad*4 .. +3
        *(uint2*)(Pw + (nq * 16 + l15) * 40 + mk * 16 + quad * 4) = pk;
      }

    // O += P.V : A[m=q][k=key(quad*8+j)] read back b128 (same-wave, in-order)
#pragma unroll
    for (int mq = 0; mq < 4; ++mq) {
      bf16x8 pa = *(const bf16x8*)(Pw + (mq * 16 + l15) * 40 + quad * 8);
#pragma unroll
      for (int nd = 0; nd < 4; ++nd)
        acc[mq][nd] = mfma16(pa, vb[nd], acc[mq][nd]);
    }
  }

  // ---- cross-wave merge ----
  // l: reduce across quads (each lane's l_part covers its quad's key rows)
#pragma unroll
  for (int nq = 0; nq < 4; ++nq) {
    l_part[nq] += __shfl_xor(l_part[nq], 16);
    l_part[nq] += __shfl_xor(l_part[nq], 32);
  }
  if (quad == 0) {
#pragma unroll
    for (int nq = 0; nq < 4; ++nq) l_buf[wave][nq * 16 + l15] = l_part[nq];
  }
  __syncthreads();  // also guards Pbuf->Obuf aliasing

  // O: sequential accumulate rounds into Obuf[d][68 q]
  for (int w = 0; w < 4; ++w) {
    if (wave == w) {
#pragma unroll
      for (int mq = 0; mq < 4; ++mq)
#pragma unroll
        for (int nd = 0; nd < 4; ++nd) {
          float* p = Obuf + (nd * 16 + l15) * 68 + mq * 16 + quad * 4;
          if (w == 0) *(f32x4*)p = acc[mq][nd];
          else {
            f32x4 v = *(const f32x4*)p;
            v += acc[mq][nd];
            *(f32x4*)p = v;
          }
        }
    }
    __syncthreads();
  }

  // output: thread t -> q = t>>2, d-group = (t&3)*16; normalize, cvt, store 32 B
  const int b_ = bh >> 4, h = bh & 15;
  const int q = t >> 2, dg = (t & 3) * 16;
  float linv = 1.f / (l_buf[0][q] + l_buf[1][q] + l_buf[2][q] + l_buf[3][q]);
  union { u16 s[16]; uint4 v[2]; } ob;
#pragma unroll
  for (int dd = 0; dd < 16; ++dd)
    ob.s[dd] = f2bf(Obuf[(dg + dd) * 68 + q] * linv);
  u16* dst = Ob + ((size_t)b_ * 2048 + q0 + q) * 1024 + h * 64 + dg;
  *(uint4*)dst = ob.v[0];
  *(uint4*)(dst + 8) = ob.v[1];
}

// ---------------- launch ----------------

extern "C" void kernel_launch(void* const* d_in, const int* in_sizes, int n_in,
                              void* d_out, int out_size, void* d_ws, size_t ws_size,
                              hipStream_t stream) {
  const float* x      = (const float*)d_in[0];
  const float* w_qkv  = (const float*)d_in[1];
  const float* b_qkv  = (const float*)d_in[2];
  const float* w_proj = (const float*)d_in[3];
  const float* b_proj = (const float*)d_in[4];
  float* out = (float*)d_out;
  char* ws = (char*)d_ws;

  // workspace layout (bytes)
  u16* xb    = (u16*)(ws);                 // 16 MB  [8192][1024]; later reused as attn_out
  u16* wqkvt = (u16*)(ws + 16777216);      //  6 MB  [3072][1024]
  u16* wprjt = (u16*)(ws + 23068672);      //  2 MB  [1024][1024]
  u16* Qb    = (u16*)(ws + 25165824);      // 16 MB  [64][2048][64]
  u16* Kb    = (u16*)(ws + 41943040);      // 16 MB
  u16* Vb    = (u16*)(ws + 58720256);      // 16 MB
  u16* Vt    = (u16*)(ws + 75497472);      // 16 MB  [64][64][2048]
  u16* Ob    = xb;                         // alias: x consumed by gemm_qkv before attn writes
  if (ws_size < 92274688u) return;  // insufficient scratch -> visible failure

  cvt_f32_bf16<<<8192, 256, 0, stream>>>(x, xb, 8388608);
  transpose_cvt<<<dim3(48, 16), 256, 0, stream>>>(w_qkv, wqkvt, 1024, 3072);
  transpose_cvt<<<dim3(16, 16), 256, 0, stream>>>(w_proj, wprjt, 1024, 1024);
  gemm_qkv<<<dim3(64, 24), 256, 0, stream>>>(xb, wqkvt, b_qkv, Qb, Kb, Vb);
  transpose_v<<<dim3(32, 64), 256, 0, stream>>>(Vb, Vt);
  attn_kernel<<<dim3(32, 64), 256, 0, stream>>>(Qb, Kb, Vt, Ob);
  gemm_proj<<<dim3(64, 8), 256, 0, stream>>>(Ob, wprjt, b_proj, out);
}

// Round 6
// 351.199 us; speedup vs baseline: 1.0022x; 1.0022x over previous
//
#include <hip/hip_runtime.h>
#include <hip/hip_bf16.h>

typedef unsigned short u16;
typedef __attribute__((ext_vector_type(8))) short bf16x8;  // 8 bf16 = 4 VGPRs
typedef __attribute__((ext_vector_type(4))) float f32x4;

// ---------------- helpers ----------------

__device__ __forceinline__ u16 f2bf(float f) {
  union { float f; unsigned u; } v; v.f = f;
  unsigned r = v.u + 0x7fffu + ((v.u >> 16) & 1u);  // RNE
  return (u16)(r >> 16);
}

// pack two fp32 -> two bf16 in one dword (HW packed cvt when available)
#if defined(__has_builtin)
#if __has_builtin(__builtin_amdgcn_cvt_pk_bf16_f32)
#define HAS_PK_BF16 1
#endif
#endif
__device__ __forceinline__ unsigned pk2bf(float a, float b) {
#ifdef HAS_PK_BF16
  typedef __attribute__((ext_vector_type(2))) __bf16 vbf2;
  union { vbf2 v; unsigned u; } u;
  u.v = __builtin_amdgcn_cvt_pk_bf16_f32(a, b);
  return u.u;
#else
  return (unsigned)f2bf(a) | ((unsigned)f2bf(b) << 16);
#endif
}

__device__ __forceinline__ f32x4 mfma16(bf16x8 a, bf16x8 b, f32x4 c) {
  return __builtin_amdgcn_mfma_f32_16x16x32_bf16(a, b, c, 0, 0, 0);
}

// async global->LDS, 16B per lane. LDS dest = wave-uniform base + lane*16.
__device__ __forceinline__ void gl_lds16(const void* g, void* l) {
  __builtin_amdgcn_global_load_lds((__attribute__((address_space(1))) void*)g,
                                   (__attribute__((address_space(3))) void*)l,
                                   16, 0, 0);
}

// stage a 128-row x 32-col bf16 tile (8 KB) from row-major global (row len ld)
__device__ __forceinline__ void stage128x32(const u16* g0, int ld, u16* lds) {
  const int t = threadIdx.x;
  const int wave = t >> 6;
#pragma unroll
  for (int j = 0; j < 2; ++j) {
    int c = j * 256 + t;                       // chunk 0..511
    const u16* gp = g0 + (size_t)(c >> 2) * ld + (c & 3) * 8;
    gl_lds16(gp, lds + (size_t)(j * 256 + wave * 64) * 8);
  }
}

// ---------------- conversion kernels ----------------

__global__ void cvt_f32_bf16(const float* __restrict__ in, u16* __restrict__ out, int n) {
  int i = (blockIdx.x * blockDim.x + threadIdx.x) * 4;
  if (i >= n) return;
  float4 v = *(const float4*)(in + i);
  u16 o0 = f2bf(v.x), o1 = f2bf(v.y), o2 = f2bf(v.z), o3 = f2bf(v.w);
  ushort4 o; o.x = o0; o.y = o1; o.z = o2; o.w = o3;
  *(ushort4*)(out + i) = o;
}

// out[c][r] = bf16(in[r][c]); in is [R][C] fp32, out is [C][R] bf16
__global__ void transpose_cvt(const float* __restrict__ in, u16* __restrict__ out,
                              int R, int C) {
  __shared__ u16 tile[64][65];
  int c0 = blockIdx.x * 64, r0 = blockIdx.y * 64;
  int lc = threadIdx.x & 63, lr = threadIdx.x >> 6;
#pragma unroll
  for (int i = 0; i < 16; ++i) {
    int r = lr + i * 4;
    tile[r][lc] = f2bf(in[(size_t)(r0 + r) * C + c0 + lc]);
  }
  __syncthreads();
#pragma unroll
  for (int i = 0; i < 16; ++i) {
    int c = lr + i * 4;
    out[(size_t)(c0 + c) * R + r0 + lc] = tile[lc][c];
  }
}

// V [bh][2048][64] -> Vt [bh][64][2048]  (bf16)
__global__ void transpose_v(const u16* __restrict__ Vb, u16* __restrict__ Vt) {
  __shared__ u16 tile[64][65];
  int bh = blockIdx.y;
  int s0 = blockIdx.x * 64;
  const u16* in = Vb + (size_t)bh * 2048 * 64;
  u16* out = Vt + (size_t)bh * 64 * 2048;
  int lc = threadIdx.x & 63, lr = threadIdx.x >> 6;
#pragma unroll
  for (int i = 0; i < 16; ++i) {
    int r = lr + i * 4;
    tile[r][lc] = in[(size_t)(s0 + r) * 64 + lc];
  }
  __syncthreads();
#pragma unroll
  for (int i = 0; i < 16; ++i) {
    int d = lr + i * 4;
    out[(size_t)d * 2048 + s0 + lc] = tile[lc][d];
  }
}

// ---------------- GEMM 1: qkv = x @ w_qkv + b_qkv ----------------
// Q pre-scaled by SCALE*log2(e) so QK^T MFMA emits exp2 arguments directly.

__global__ __launch_bounds__(256, 2) void gemm_qkv(
    const u16* __restrict__ A, const u16* __restrict__ Bt,
    const float* __restrict__ bias,
    u16* __restrict__ Qb, u16* __restrict__ Kb, u16* __restrict__ Vb) {
  __shared__ u16 As[128 * 32], Bs[128 * 32];
  const int row0 = blockIdx.x * 128, col0 = blockIdx.y * 128;
  const int t = threadIdx.x, lane = t & 63, wave = t >> 6;
  const int quad = lane >> 4, l15 = lane & 15;
  const int m_off = (wave & 1) * 64, n_off = (wave >> 1) * 64;
  f32x4 acc[4][4] = {};
  for (int k0 = 0; k0 < 1024; k0 += 32) {
    __syncthreads();
    stage128x32(A + (size_t)row0 * 1024 + k0, 1024, As);
    stage128x32(Bt + (size_t)col0 * 1024 + k0, 1024, Bs);
    __syncthreads();
    bf16x8 a[4], b[4];
#pragma unroll
    for (int mi = 0; mi < 4; ++mi)
      a[mi] = *(const bf16x8*)(As + (m_off + mi * 16 + l15) * 32 + quad * 8);
#pragma unroll
    for (int ni = 0; ni < 4; ++ni)
      b[ni] = *(const bf16x8*)(Bs + (n_off + ni * 16 + l15) * 32 + quad * 8);
#pragma unroll
    for (int mi = 0; mi < 4; ++mi)
#pragma unroll
      for (int ni = 0; ni < 4; ++ni)
        acc[mi][ni] = mfma16(a[mi], b[ni], acc[mi][ni]);
  }
  const int which = col0 >> 10;  // block-uniform: 0=Q 1=K 2=V
  u16* dst = which == 0 ? Qb : (which == 1 ? Kb : Vb);
  const float qscale = which == 0 ? 0.1803368801111137f : 1.0f;  // 0.125*log2(e)
#pragma unroll
  for (int ni = 0; ni < 4; ++ni) {
    int col = col0 + n_off + ni * 16 + l15;
    float bv = bias[col];
    int h = (col >> 6) & 15, d = col & 63;
#pragma unroll
    for (int mi = 0; mi < 4; ++mi) {
#pragma unroll
      for (int r = 0; r < 4; ++r) {
        int row = row0 + m_off + mi * 16 + quad * 4 + r;  // b*2048 + s
        int bb = row >> 11, s = row & 2047;
        float v = (acc[mi][ni][r] + bv) * qscale;
        dst[(((size_t)bb * 16 + h) * 2048 + s) * 64 + d] = f2bf(v);
      }
    }
  }
}

// ---------------- GEMM 2: out = attn_out @ w_proj + b_proj (fp32 out) ----------------

__global__ __launch_bounds__(256, 2) void gemm_proj(
    const u16* __restrict__ A, const u16* __restrict__ Bt,
    const float* __restrict__ bias, float* __restrict__ C) {
  __shared__ u16 As[128 * 32], Bs[128 * 32];
  const int row0 = blockIdx.x * 128, col0 = blockIdx.y * 128;
  const int t = threadIdx.x, lane = t & 63, wave = t >> 6;
  const int quad = lane >> 4, l15 = lane & 15;
  const int m_off = (wave & 1) * 64, n_off = (wave >> 1) * 64;
  f32x4 acc[4][4] = {};
  for (int k0 = 0; k0 < 1024; k0 += 32) {
    __syncthreads();
    stage128x32(A + (size_t)row0 * 1024 + k0, 1024, As);
    stage128x32(Bt + (size_t)col0 * 1024 + k0, 1024, Bs);
    __syncthreads();
    bf16x8 a[4], b[4];
#pragma unroll
    for (int mi = 0; mi < 4; ++mi)
      a[mi] = *(const bf16x8*)(As + (m_off + mi * 16 + l15) * 32 + quad * 8);
#pragma unroll
    for (int ni = 0; ni < 4; ++ni)
      b[ni] = *(const bf16x8*)(Bs + (n_off + ni * 16 + l15) * 32 + quad * 8);
#pragma unroll
    for (int mi = 0; mi < 4; ++mi)
#pragma unroll
      for (int ni = 0; ni < 4; ++ni)
        acc[mi][ni] = mfma16(a[mi], b[ni], acc[mi][ni]);
  }
#pragma unroll
  for (int ni = 0; ni < 4; ++ni) {
    int col = col0 + n_off + ni * 16 + l15;
    float bv = bias[col];
#pragma unroll
    for (int mi = 0; mi < 4; ++mi) {
#pragma unroll
      for (int r = 0; r < 4; ++r) {
        int row = row0 + m_off + mi * 16 + quad * 4 + r;
        C[(size_t)row * 1024 + col] = acc[mi][ni][r] + bv;
      }
    }
  }
}

// ---------------- Flash attention v3.1: key-split waves + XCD-local block swizzle ------
// Q,K: [bh][2048][64] bf16 (Q pre-scaled by 0.125*log2e); Vt: [bh][64][2048] bf16.
// p = exp2(s), no shift (|s|max ~ 9; l-normalization cancels scale exactly).
// Waves split KEYS (order-free sum): block = 64 q, 4 waves; wave w owns keys
// {it*128 + w*32 .. +31}. K/V/Q load global->VGPR b128.
// XCD locality (the R4 fix): 1-D grid, XCD = id%8 (measured m09). Swizzle
//   bh = (id&7) + 8*(id>>8), qt = (id>>3)&31
// puts all 32 q-tile blocks of a head on ONE XCD, dispatched consecutively ->
// K/V (0.5 MB/head) stays L2-resident; re-reads (1 GB) served at L2 BW.
// P round-trips a per-wave 5 KB LDS scratch (b64 write / b128 read, no barrier).

__global__ __launch_bounds__(256, 3) void attn_kernel(
    const u16* __restrict__ Qb, const u16* __restrict__ Kb,
    const u16* __restrict__ Vt, u16* __restrict__ Ob) {
  __shared__ u16 Pbuf[4][64 * 40];   // per-wave P [64 q][32 key], row pitch 40 u16
  __shared__ float l_buf[4][64];
  float* Obuf = (float*)&Pbuf[0][0]; // reused as [64 d][68 q] f32 after final barrier

  const int id = blockIdx.x;
  const int bh = (id & 7) | ((id >> 8) << 3);  // XCD-local head assignment
  const int q0 = ((id >> 3) & 31) * 64;
  const u16* Qp = Qb + (size_t)bh * 2048 * 64;
  const u16* Kp = Kb + (size_t)bh * 2048 * 64;
  const u16* Vp = Vt + (size_t)bh * 64 * 2048;
  const int t = threadIdx.x, lane = t & 63, wave = t >> 6;
  const int quad = lane >> 4, l15 = lane & 15;
  u16* Pw = &Pbuf[wave][0];

  // Q fragments in registers for the whole kernel: B[k=d][n=q]
  bf16x8 qf[2][4];
#pragma unroll
  for (int ks = 0; ks < 2; ++ks)
#pragma unroll
    for (int nq = 0; nq < 4; ++nq)
      qf[ks][nq] = *(const bf16x8*)(Qp + (size_t)(q0 + nq * 16 + l15) * 64 + ks * 32 + quad * 8);

  float l_part[4] = {0.f, 0.f, 0.f, 0.f};
  f32x4 acc[4][4] = {};  // [mq][nd]: O rows q=mq*16+quad*4+r, cols d=nd*16+l15

  for (int it = 0; it < 16; ++it) {
    const int key0 = it * 128 + wave * 32;
    // K fragments: A[m=key][k=d]
    bf16x8 kf[2][2];
#pragma unroll
    for (int mk = 0; mk < 2; ++mk)
#pragma unroll
      for (int ks = 0; ks < 2; ++ks)
        kf[mk][ks] = *(const bf16x8*)(Kp + (size_t)(key0 + mk * 16 + l15) * 64 + ks * 32 + quad * 8);
    // V fragments: B[k=key][n=d] from Vt[d][key]
    bf16x8 vb[4];
#pragma unroll
    for (int nd = 0; nd < 4; ++nd)
      vb[nd] = *(const bf16x8*)(Vp + (size_t)(nd * 16 + l15) * 2048 + key0 + quad * 8);

    // S^T = K.Q^T : C[row=key=mk*16+quad*4+r][col=q=nq*16+l15]
    f32x4 s[2][4] = {};
#pragma unroll
    for (int ks = 0; ks < 2; ++ks)
#pragma unroll
      for (int mk = 0; mk < 2; ++mk)
#pragma unroll
        for (int nq = 0; nq < 4; ++nq)
          s[mk][nq] = mfma16(kf[mk][ks], qf[ks][nq], s[mk][nq]);

    // p = exp2(s); accumulate l; write P to private LDS in PV A-layout
#pragma unroll
    for (int mk = 0; mk < 2; ++mk)
#pragma unroll
      for (int nq = 0; nq < 4; ++nq) {
        float p0 = __builtin_amdgcn_exp2f(s[mk][nq][0]);
        float p1 = __builtin_amdgcn_exp2f(s[mk][nq][1]);
        float p2 = __builtin_amdgcn_exp2f(s[mk][nq][2]);
        float p3 = __builtin_amdgcn_exp2f(s[mk][nq][3]);
        l_part[nq] += (p0 + p1) + (p2 + p3);
        uint2 pk; pk.x = pk2bf(p0, p1); pk.y = pk2bf(p2, p3);
        // row q = nq*16+l15 (40 u16 pitch), cols key mk*16+quad*4 .. +3
        *(uint2*)(Pw + (nq * 16 + l15) * 40 + mk * 16 + quad * 4) = pk;
      }

    // O += P.V : A[m=q][k=key(quad*8+j)] read back b128 (same-wave, in-order)
#pragma unroll
    for (int mq = 0; mq < 4; ++mq) {
      bf16x8 pa = *(const bf16x8*)(Pw + (mq * 16 + l15) * 40 + quad * 8);
#pragma unroll
      for (int nd = 0; nd < 4; ++nd)
        acc[mq][nd] = mfma16(pa, vb[nd], acc[mq][nd]);
    }
  }

  // ---- cross-wave merge ----
  // l: reduce across quads (each lane's l_part covers its quad's key rows)
#pragma unroll
  for (int nq = 0; nq < 4; ++nq) {
    l_part[nq] += __shfl_xor(l_part[nq], 16);
    l_part[nq] += __shfl_xor(l_part[nq], 32);
  }
  if (quad == 0) {
#pragma unroll
    for (int nq = 0; nq < 4; ++nq) l_buf[wave][nq * 16 + l15] = l_part[nq];
  }
  __syncthreads();  // also guards Pbuf->Obuf aliasing

  // O: sequential accumulate rounds into Obuf[d][68 q]
  for (int w = 0; w < 4; ++w) {
    if (wave == w) {
#pragma unroll
      for (int mq = 0; mq < 4; ++mq)
#pragma unroll
        for (int nd = 0; nd < 4; ++nd) {
          float* p = Obuf + (nd * 16 + l15) * 68 + mq * 16 + quad * 4;
          if (w == 0) *(f32x4*)p = acc[mq][nd];
          else {
            f32x4 v = *(const f32x4*)p;
            v += acc[mq][nd];
            *(f32x4*)p = v;
          }
        }
    }
    __syncthreads();
  }

  // output: thread t -> q = t>>2, d-group = (t&3)*16; normalize, cvt, store 32 B
  const int b_ = bh >> 4, h = bh & 15;
  const int q = t >> 2, dg = (t & 3) * 16;
  float linv = 1.f / (l_buf[0][q] + l_buf[1][q] + l_buf[2][q] + l_buf[3][q]);
  union { u16 s[16]; uint4 v[2]; } ob;
#pragma unroll
  for (int dd = 0; dd < 16; ++dd)
    ob.s[dd] = f2bf(Obuf[(dg + dd) * 68 + q] * linv);
  u16* dst = Ob + ((size_t)b_ * 2048 + q0 + q) * 1024 + h * 64 + dg;
  *(uint4*)dst = ob.v[0];
  *(uint4*)(dst + 8) = ob.v[1];
}

// ---------------- launch ----------------

extern "C" void kernel_launch(void* const* d_in, const int* in_sizes, int n_in,
                              void* d_out, int out_size, void* d_ws, size_t ws_size,
                              hipStream_t stream) {
  const float* x      = (const float*)d_in[0];
  const float* w_qkv  = (const float*)d_in[1];
  const float* b_qkv  = (const float*)d_in[2];
  const float* w_proj = (const float*)d_in[3];
  const float* b_proj = (const float*)d_in[4];
  float* out = (float*)d_out;
  char* ws = (char*)d_ws;

  // workspace layout (bytes)
  u16* xb    = (u16*)(ws);                 // 16 MB  [8192][1024]; later reused as attn_out
  u16* wqkvt = (u16*)(ws + 16777216);      //  6 MB  [3072][1024]
  u16* wprjt = (u16*)(ws + 23068672);      //  2 MB  [1024][1024]
  u16* Qb    = (u16*)(ws + 25165824);      // 16 MB  [64][2048][64]
  u16* Kb    = (u16*)(ws + 41943040);      // 16 MB
  u16* Vb    = (u16*)(ws + 58720256);      // 16 MB
  u16* Vt    = (u16*)(ws + 75497472);      // 16 MB  [64][64][2048]
  u16* Ob    = xb;                         // alias: x consumed by gemm_qkv before attn writes
  if (ws_size < 92274688u) return;  // insufficient scratch -> visible failure

  cvt_f32_bf16<<<8192, 256, 0, stream>>>(x, xb, 8388608);
  transpose_cvt<<<dim3(48, 16), 256, 0, stream>>>(w_qkv, wqkvt, 1024, 3072);
  transpose_cvt<<<dim3(16, 16), 256, 0, stream>>>(w_proj, wprjt, 1024, 1024);
  gemm_qkv<<<dim3(64, 24), 256, 0, stream>>>(xb, wqkvt, b_qkv, Qb, Kb, Vb);
  transpose_v<<<dim3(32, 64), 256, 0, stream>>>(Vb, Vt);
  attn_kernel<<<dim3(2048), 256, 0, stream>>>(Qb, Kb, Vt, Ob);
  gemm_proj<<<dim3(64, 8), 256, 0, stream>>>(Ob, wprjt, b_proj, out);
}